// Round 9
// baseline (411.999 us; speedup 1.0000x reference)
//
#include <hip/hip_runtime.h>
#include <math.h>

#define NSN 4760
#define KNN 16
#define NT 6
#define NB 16
#define NGB 595    // n-groups per batch: 595*8 = 4760
#define NBLK 85    // blocks per batch: 85 * 7 = 595 (uniform)

__device__ __forceinline__ float rl_f(float v, int lane) {
  return __builtin_bit_cast(float, __builtin_amdgcn_readlane(__builtin_bit_cast(int, v), lane));
}

// ============ Merged precompute: sensor (0..148) | latent (149..172) | consts (173)
// Sensor: S, qlocal, qg, c01, SS=(S, SM) per sensor (batch independent)
// Latent: kg, TBL=(VW pair, VWM) per (b,t,h)
// Consts: WA WB G P C1 folds
__global__ void precompute_all(const float* __restrict__ pos_emb,
    const float* __restrict__ face_emb, const int* __restrict__ face_ids,
    const float* __restrict__ W_nbr, const float* __restrict__ b_nbr,
    const float* __restrict__ W_ql, const float* __restrict__ b_ql,
    const float* __restrict__ W_qg, const float* __restrict__ b_qg,
    const float* __restrict__ latent,
    const float* __restrict__ W_lat, const float* __restrict__ b_lat,
    const float* __restrict__ W_lf, const float* __restrict__ b_lf,
    const float* __restrict__ W_k, const float* __restrict__ b_k,
    const float* __restrict__ W_v, const float* __restrict__ b_v,
    const float* __restrict__ W_go, const float* __restrict__ b_go,
    const float* __restrict__ W_m1, const float* __restrict__ b_m1,
    const float* __restrict__ ln_g, const float* __restrict__ ln_b,
    float* __restrict__ S, float* __restrict__ qlocal,
    float* __restrict__ qg, float* __restrict__ c01, float2* __restrict__ SS,
    float* __restrict__ kg, float4* __restrict__ TBL, float* __restrict__ C)
{
  __shared__ __align__(16) float qT[8][128][4];       // sensor: 16 KB
  __shared__ __align__(16) float lat[4][1024];        // latent: 16 KB
  __shared__ __align__(16) float kvS[4][128];
  __shared__ __align__(16) float vrow[4][128];
  __shared__ __align__(16) float vwl[4][4][128];      // 8 KB
  const int bid = blockIdx.x;
  const int tid = threadIdx.x;

  if (bid < 149) {
    // ---------------- sensor part: wave = 4 sensors ----------------
    const int w = tid >> 6, lane = tid & 63;
    const int grp = bid * 8 + w;
    if (grp >= NSN / 4) return;
    const int n0 = grp * 4;
    #pragma unroll
    for (int si = 0; si < 4; ++si) {
      const int n = n0 + si;
      const int fid = face_ids[n];
      const int e1 = lane + 64;
      qT[w][lane][si] = pos_emb[n * 96 + lane];
      qT[w][e1][si] = (e1 < 96) ? pos_emb[n * 96 + e1] : face_emb[fid * 32 + (e1 - 96)];
    }
    const float bn = b_nbr[lane], bq = b_ql[lane];
    const float bg0 = b_qg[lane], bg1 = b_qg[lane + 64];
    float s[4], ql[4], g0[4], g1[4];
    #pragma unroll
    for (int si = 0; si < 4; ++si) { s[si] = bn; ql[si] = bq; g0[si] = bg0; g1[si] = bg1; }
    #pragma unroll 2
    for (int i = 0; i < 128; ++i) {
      const float wn  = W_nbr[(2 + i) * 64 + lane];
      const float wq  = W_ql[i * 64 + lane];
      const float wg0 = W_qg[i * 128 + lane];
      const float wg1 = W_qg[i * 128 + 64 + lane];
      const float4 qv = *(const float4*)&qT[w][i][0];
      s[0]  += qv.x * wn;  s[1]  += qv.y * wn;  s[2]  += qv.z * wn;  s[3]  += qv.w * wn;
      ql[0] += qv.x * wq;  ql[1] += qv.y * wq;  ql[2] += qv.z * wq;  ql[3] += qv.w * wq;
      g0[0] += qv.x * wg0; g0[1] += qv.y * wg0; g0[2] += qv.z * wg0; g0[3] += qv.w * wg0;
      g1[0] += qv.x * wg1; g1[1] += qv.y * wg1; g1[2] += qv.z * wg1; g1[3] += qv.w * wg1;
    }
    const float wn0 = W_nbr[lane], wn1 = W_nbr[64 + lane];
    #pragma unroll
    for (int si = 0; si < 4; ++si) {
      const int n = n0 + si;
      S[n * 64 + lane] = s[si];
      qlocal[n * 64 + lane] = ql[si];
      qg[n * 128 + lane] = g0[si];
      qg[n * 128 + 64 + lane] = g1[si];
      float p0 = wn0 * ql[si], p1 = wn1 * ql[si];
      #pragma unroll
      for (int o = 32; o; o >>= 1) { p0 += __shfl_xor(p0, o); p1 += __shfl_xor(p1, o); }
      if (lane == 0) { c01[2 * n] = p0; c01[2 * n + 1] = p1; }
    }
    const float gl = ln_g[lane];
    #pragma unroll
    for (int si = 0; si < 4; ++si) qT[w][lane][si] = s[si] * gl;
    float sm0 = 0.f, sm1 = 0.f, sm2 = 0.f, sm3 = 0.f;
    #pragma unroll 4
    for (int h = 0; h < 64; ++h) {
      const float w1v = W_m1[h * 64 + lane];
      const float4 sv = *(const float4*)&qT[w][h][0];
      sm0 += sv.x * w1v; sm1 += sv.y * w1v; sm2 += sv.z * w1v; sm3 += sv.w * w1v;
    }
    SS[(n0 + 0) * 64 + lane] = make_float2(s[0], sm0);
    SS[(n0 + 1) * 64 + lane] = make_float2(s[1], sm1);
    SS[(n0 + 2) * 64 + lane] = make_float2(s[2], sm2);
    SS[(n0 + 3) * 64 + lane] = make_float2(s[3], sm3);
  } else if (bid < 173) {
    // ---------------- latent part: 4 teams x 128 threads, bt = 0..95 ------
    const int team = tid >> 7, o = tid & 127;
    const int bt = (bid - 149) * 4 + team;
    const int t = bt % NT;
    for (int i = o; i < 1024; i += 128) lat[team][i] = latent[bt * 1024 + i];
    __syncthreads();
    float acc = b_lat[o] + b_lf[o];
    #pragma unroll 8
    for (int i = 0; i < 1024; ++i) acc += lat[team][i] * W_lat[i * 128 + o];
    #pragma unroll
    for (int i = 0; i < 32; ++i) acc += face_emb[t * 32 + i] * W_lf[i * 128 + o];
    kvS[team][o] = acc;
    __syncthreads();
    float kk = b_k[o], vv = b_v[o];
    #pragma unroll 4
    for (int i = 0; i < 128; ++i) {
      const float c = kvS[team][i];
      kk += c * W_k[i * 128 + o];
      vv += c * W_v[i * 128 + o];
    }
    kg[bt * 128 + o] = kk;
    vrow[team][o] = vv;
    __syncthreads();
    #pragma unroll
    for (int h = 0; h < 4; ++h) {
      float a = 0.f;
      #pragma unroll 8
      for (int i = 0; i < 32; ++i)
        a += vrow[team][h * 32 + i] * W_go[(h * 32 + i) * 128 + o];
      vwl[team][h][o] = a;
    }
    __syncthreads();
    if (o < 64) {
      #pragma unroll
      for (int h = 0; h < 4; ++h) {
        float m = 0.f;
        #pragma unroll 4
        for (int i = 0; i < 128; ++i)
          m += vwl[team][h][i] * ln_g[64 + i] * W_m1[(64 + i) * 64 + o];
        TBL[(bt * 4 + h) * 64 + o] =
            make_float4(vwl[team][h][2 * o], vwl[team][h][2 * o + 1], m, 0.f);
      }
    }
  } else {
    // ---------------- consts part ----------------
    const int o = tid;
    if (o < 64) {
      float wa = 0.f, wb = 0.f;
      #pragma unroll 4
      for (int h = 0; h < 64; ++h) {
        const float gw = ln_g[h] * W_m1[h * 64 + o];
        wa += W_nbr[h] * gw;
        wb += W_nbr[64 + h] * gw;
      }
      C[o] = wa; C[64 + o] = wb;
      float g = 0.f, p = 0.f;
      #pragma unroll 4
      for (int d = 0; d < 192; ++d) {
        const float w1 = W_m1[d * 64 + o];
        g += ln_g[d] * w1;
        p += ln_b[d] * w1;
      }
      C[128 + o] = g; C[192 + o] = p + b_m1[o];
      float c1 = 0.f;
      #pragma unroll 4
      for (int i = 0; i < 128; ++i)
        c1 += b_go[i] * ln_g[64 + i] * W_m1[(64 + i) * 64 + o];
      C[256 + o] = c1;
    }
  }
}

// ============ Main fused kernel: block = (b, 85-stride over n-groups) ======
// wave = one (b,n) item per iteration; 7 iterations per wave.
__launch_bounds__(512, 2)
__global__ void fused_main(const float* __restrict__ x_flat,
    const int* __restrict__ mask, const int* __restrict__ knn,
    const float* __restrict__ Wnbr,
    const float* __restrict__ S, const float* __restrict__ qlocal,
    const float* __restrict__ qg, const float* __restrict__ c01,
    const float* __restrict__ kg, const float2* __restrict__ SS,
    const float4* __restrict__ TBL, const float* __restrict__ CONSTS,
    const float* __restrict__ bgo, const float* __restrict__ Wm2,
    const float* __restrict__ bm2, float* __restrict__ out)
{
  __shared__ __align__(16) float4 TBLl[NT * 4 * 64];  // 24 KB
  __shared__ __align__(16) float kgl[NT * 128];       // 3 KB
  __shared__ __align__(16) float qlS[8][64];          // 2 KB -> 29 KB

  const int tid = threadIdx.x;
  const int b = blockIdx.x / NBLK;
  const int bg = blockIdx.x - b * NBLK;

  {
    const float4* tb = TBL + b * (NT * 4 * 64);
    for (int i = tid; i < NT * 4 * 64; i += 512) TBLl[i] = tb[i];
    const float* kgb = kg + b * (NT * 128);
    for (int i = tid; i < NT * 128; i += 512) kgl[i] = kgb[i];
  }
  __syncthreads();

  const int w = tid >> 6, lane = tid & 63;

  // hoisted per-lane folded constants (reused across 7 items)
  const float wa  = CONSTS[lane],       wbc = CONSTS[64 + lane];
  const float cg  = CONSTS[128 + lane], cp  = CONSTS[192 + lane];
  const float cc1 = CONSTS[256 + lane];
  const float w0 = Wnbr[lane], w1 = Wnbr[64 + lane];
  const float2 bgov = *(const float2*)(bgo + 2 * lane);
  const float wm2 = Wm2[lane], bm2s = bm2[0];

  for (int ng = bg; ng < NGB; ng += NBLK) {
    const int n = ng * 8 + w;
    const int item = b * NSN + n;

    // ---- early independent loads ----
    const float2 c01v = *(const float2*)(c01 + 2 * n);
    const int mself = mask[item];
    const float ql = qlocal[n * 64 + lane];
    const float2 q2 = *(const float2*)(qg + n * 128 + 2 * lane);
    int jv = 0, mk = 0; float x0 = 0.f, x1 = 0.f;
    if (lane < 16) {
      jv = knn[n * 16 + lane];
      const float2 x01 = *(const float2*)(x_flat + (size_t)(b * NSN + jv) * 2);
      x0 = x01.x; x1 = x01.y;
      mk = mask[b * NSN + jv];
    }
    qlS[w][lane] = ql;

    // ---- Pass 1: KNN logits (4 lanes per neighbor k) ----
    const int k = lane >> 2, d = lane & 3;
    const int jk = __shfl(jv, k);
    const float4* Sr = (const float4*)(S + jk * 64 + d * 16);
    const float4* qr = (const float4*)(&qlS[w][d * 16]);
    float acc = 0.f;
    #pragma unroll
    for (int i = 0; i < 4; ++i) {
      const float4 sv = Sr[i]; const float4 qv = qr[i];
      acc += sv.x * qv.x + sv.y * qv.y + sv.z * qv.z + sv.w * qv.w;
    }
    acc += __shfl_xor(acc, 1); acc += __shfl_xor(acc, 2);
    const float xk0 = __shfl(x0, k), xk1 = __shfl(x1, k);
    const int mkk = __shfl(mk, k);
    float logit = (acc + xk0 * c01v.x + xk1 * c01v.y) * 0.125f;
    if (mkk != 0) logit = -10000.0f;
    float mx = logit;
    mx = fmaxf(mx, __shfl_xor(mx, 4));  mx = fmaxf(mx, __shfl_xor(mx, 8));
    mx = fmaxf(mx, __shfl_xor(mx, 16)); mx = fmaxf(mx, __shfl_xor(mx, 32));
    const float e = __expf(logit - mx);
    float s4 = e;
    s4 += __shfl_xor(s4, 4); s4 += __shfl_xor(s4, 8);
    s4 += __shfl_xor(s4, 16); s4 += __shfl_xor(s4, 32);
    const float attn = e / s4;
    float ax0 = attn * xk0, ax1 = attn * xk1;
    ax0 += __shfl_xor(ax0, 4); ax0 += __shfl_xor(ax0, 8);
    ax0 += __shfl_xor(ax0, 16); ax0 += __shfl_xor(ax0, 32);
    ax1 += __shfl_xor(ax1, 4); ax1 += __shfl_xor(ax1, 8);
    ax1 += __shfl_xor(ax1, 16); ax1 += __shfl_xor(ax1, 32);

    // ---- lf/L: 16 packed row-gathers, 4-batched for MLP (ILP) ----
    float lf = ax0 * w0 + ax1 * w1;
    float L  = ax0 * wa + ax1 * wbc;
    #pragma unroll
    for (int kb = 0; kb < 4; ++kb) {
      const int j0 = __builtin_amdgcn_readlane(jv, 4 * kb + 0);
      const int j1 = __builtin_amdgcn_readlane(jv, 4 * kb + 1);
      const int j2 = __builtin_amdgcn_readlane(jv, 4 * kb + 2);
      const int j3 = __builtin_amdgcn_readlane(jv, 4 * kb + 3);
      const float a0 = rl_f(attn, 16 * kb + 0);
      const float a1 = rl_f(attn, 16 * kb + 4);
      const float a2 = rl_f(attn, 16 * kb + 8);
      const float a3 = rl_f(attn, 16 * kb + 12);
      const float2 s0 = SS[j0 * 64 + lane];
      const float2 s1 = SS[j1 * 64 + lane];
      const float2 s2 = SS[j2 * 64 + lane];
      const float2 s3 = SS[j3 * 64 + lane];
      lf += a0 * s0.x + a1 * s1.x + a2 * s2.x + a3 * s3.x;
      L  += a0 * s0.y + a1 * s1.y + a2 * s2.y + a3 * s3.y;
    }

    // ---- global attention (head h = lane>>4, dims 2l,2l+1), prefetched ----
    float2 k2v[NT];
    #pragma unroll
    for (int t = 0; t < NT; ++t) k2v[t] = *(const float2*)&kgl[t * 128 + 2 * lane];
    float av[NT];
    #pragma unroll
    for (int t = 0; t < NT; ++t) {
      float p = q2.x * k2v[t].x + q2.y * k2v[t].y;
      p += __shfl_xor(p, 1); p += __shfl_xor(p, 2);
      p += __shfl_xor(p, 4); p += __shfl_xor(p, 8);
      av[t] = p * 0.17677669529663687f;   // 1/sqrt(32)
    }
    float gm = av[0];
    #pragma unroll
    for (int t = 1; t < NT; ++t) gm = fmaxf(gm, av[t]);
    float gs = 0.f;
    #pragma unroll
    for (int t = 0; t < NT; ++t) { av[t] = __expf(av[t] - gm); gs += av[t]; }
    const float ginv = 1.0f / gs;
    #pragma unroll
    for (int t = 0; t < NT; ++t) av[t] *= ginv;

    // ---- g_out + M from packed table, 4-batched reads ----
    float g0 = bgov.x, g1 = bgov.y, M = 0.f;
    #pragma unroll
    for (int t = 0; t < NT; ++t) {
      const float4 r0 = TBLl[(t * 4 + 0) * 64 + lane];
      const float4 r1 = TBLl[(t * 4 + 1) * 64 + lane];
      const float4 r2 = TBLl[(t * 4 + 2) * 64 + lane];
      const float4 r3 = TBLl[(t * 4 + 3) * 64 + lane];
      const float a0 = rl_f(av[t], 0);
      const float a1 = rl_f(av[t], 16);
      const float a2 = rl_f(av[t], 32);
      const float a3 = rl_f(av[t], 48);
      g0 += a0 * r0.x + a1 * r1.x + a2 * r2.x + a3 * r3.x;
      g1 += a0 * r0.y + a1 * r1.y + a2 * r2.y + a3 * r3.y;
      M  += a0 * r0.z + a1 * r1.z + a2 * r2.z + a3 * r3.z;
    }

    // ---- LayerNorm stats over 192 ----
    float s1 = lf + g0 + g1;
    float s2 = lf * lf + g0 * g0 + g1 * g1;
    #pragma unroll
    for (int o = 32; o; o >>= 1) { s1 += __shfl_xor(s1, o); s2 += __shfl_xor(s2, o); }
    const float mu  = s1 * (1.0f / 192.0f);
    const float var = s2 * (1.0f / 192.0f) - mu * mu;
    const float rinv = rsqrtf(var + 1e-5f);

    // ---- folded MLP ----
    const float m1 = rinv * (L + M + cc1 - mu * cg) + cp;
    const float gelu = 0.5f * m1 * (1.0f + erff(m1 * 0.7071067811865476f));
    float pr = gelu * wm2;
    #pragma unroll
    for (int o = 32; o; o >>= 1) pr += __shfl_xor(pr, o);
    float res = pr + bm2s;
    if (mself == 0) res = 0.f;
    if (lane == 0) out[item] = res;
  }
}

extern "C" void kernel_launch(void* const* d_in, const int* in_sizes, int n_in,
                              void* d_out, int out_size, void* d_ws, size_t ws_size,
                              hipStream_t stream) {
  (void)in_sizes; (void)n_in; (void)out_size; (void)ws_size;
  const float* x_flat   = (const float*)d_in[0];
  const float* latent   = (const float*)d_in[1];
  const float* pos_emb  = (const float*)d_in[2];
  const float* face_emb = (const float*)d_in[3];
  const float* W_nbr = (const float*)d_in[4];
  const float* b_nbr = (const float*)d_in[5];
  const float* W_ql  = (const float*)d_in[6];
  const float* b_ql  = (const float*)d_in[7];
  const float* W_lat = (const float*)d_in[8];
  const float* b_lat = (const float*)d_in[9];
  const float* W_lf  = (const float*)d_in[10];
  const float* b_lf  = (const float*)d_in[11];
  const float* W_qg  = (const float*)d_in[12];
  const float* b_qg  = (const float*)d_in[13];
  const float* W_k   = (const float*)d_in[14];
  const float* b_k   = (const float*)d_in[15];
  const float* W_v   = (const float*)d_in[16];
  const float* b_v   = (const float*)d_in[17];
  const float* W_go  = (const float*)d_in[18];
  const float* b_go  = (const float*)d_in[19];
  const float* ln_g  = (const float*)d_in[20];
  const float* ln_b  = (const float*)d_in[21];
  const float* W_m1  = (const float*)d_in[22];
  const float* b_m1  = (const float*)d_in[23];
  const float* W_m2  = (const float*)d_in[24];
  const float* b_m2  = (const float*)d_in[25];
  const int* mask     = (const int*)d_in[26];
  const int* knn      = (const int*)d_in[27];
  const int* face_ids = (const int*)d_in[28];
  float* out = (float*)d_out;

  float* ws = (float*)d_ws;
  float* S      = ws;  ws += NSN * 64;
  float* qlocal = ws;  ws += NSN * 64;
  float* qgb    = ws;  ws += NSN * 128;
  float* c01    = ws;  ws += NSN * 2;
  float2* SSt   = (float2*)ws;  ws += NSN * 64 * 2;
  float* kgb    = ws;  ws += NB * NT * 128;
  float4* TBLt  = (float4*)ws;  ws += NB * NT * 4 * 64 * 4;
  float* CONSTS = ws;  ws += 5 * 64;

  precompute_all<<<174, 512, 0, stream>>>(pos_emb, face_emb, face_ids,
      W_nbr, b_nbr, W_ql, b_ql, W_qg, b_qg,
      latent, W_lat, b_lat, W_lf, b_lf, W_k, b_k, W_v, b_v,
      W_go, b_go, W_m1, b_m1, ln_g, ln_b,
      S, qlocal, qgb, c01, SSt, kgb, TBLt, CONSTS);
  fused_main<<<NB * NBLK, 512, 0, stream>>>(x_flat, mask, knn, W_nbr,
      S, qlocal, qgb, c01, kgb, SSt, TBLt, CONSTS,
      b_go, W_m2, b_m2, out);
}

// Round 10
// 297.147 us; speedup vs baseline: 1.3865x; 1.3865x over previous
//
#include <hip/hip_runtime.h>
#include <math.h>

#define NSN 4760
#define KNN 16
#define NT 6
#define NB 16
#define NGB 595    // n-groups per batch: 595*8 = 4760

__device__ __forceinline__ float rl_f(float v, int lane) {
  return __builtin_bit_cast(float, __builtin_amdgcn_readlane(__builtin_bit_cast(int, v), lane));
}

// ============ Merged precompute: sensor (0..148) | latent (149..172) | consts (173)
__global__ void precompute_all(const float* __restrict__ pos_emb,
    const float* __restrict__ face_emb, const int* __restrict__ face_ids,
    const float* __restrict__ W_nbr, const float* __restrict__ b_nbr,
    const float* __restrict__ W_ql, const float* __restrict__ b_ql,
    const float* __restrict__ W_qg, const float* __restrict__ b_qg,
    const float* __restrict__ latent,
    const float* __restrict__ W_lat, const float* __restrict__ b_lat,
    const float* __restrict__ W_lf, const float* __restrict__ b_lf,
    const float* __restrict__ W_k, const float* __restrict__ b_k,
    const float* __restrict__ W_v, const float* __restrict__ b_v,
    const float* __restrict__ W_go, const float* __restrict__ b_go,
    const float* __restrict__ W_m1, const float* __restrict__ b_m1,
    const float* __restrict__ ln_g, const float* __restrict__ ln_b,
    float* __restrict__ S, float* __restrict__ qlocal,
    float* __restrict__ qg, float* __restrict__ c01, float2* __restrict__ SS,
    float* __restrict__ kg, float4* __restrict__ TBL, float* __restrict__ C)
{
  __shared__ __align__(16) float qT[8][128][4];
  __shared__ __align__(16) float lat[4][1024];
  __shared__ __align__(16) float kvS[4][128];
  __shared__ __align__(16) float vrow[4][128];
  __shared__ __align__(16) float vwl[4][4][128];
  const int bid = blockIdx.x;
  const int tid = threadIdx.x;

  if (bid < 149) {
    const int w = tid >> 6, lane = tid & 63;
    const int grp = bid * 8 + w;
    if (grp >= NSN / 4) return;
    const int n0 = grp * 4;
    #pragma unroll
    for (int si = 0; si < 4; ++si) {
      const int n = n0 + si;
      const int fid = face_ids[n];
      const int e1 = lane + 64;
      qT[w][lane][si] = pos_emb[n * 96 + lane];
      qT[w][e1][si] = (e1 < 96) ? pos_emb[n * 96 + e1] : face_emb[fid * 32 + (e1 - 96)];
    }
    const float bn = b_nbr[lane], bq = b_ql[lane];
    const float bg0 = b_qg[lane], bg1 = b_qg[lane + 64];
    float s[4], ql[4], g0[4], g1[4];
    #pragma unroll
    for (int si = 0; si < 4; ++si) { s[si] = bn; ql[si] = bq; g0[si] = bg0; g1[si] = bg1; }
    #pragma unroll 2
    for (int i = 0; i < 128; ++i) {
      const float wn  = W_nbr[(2 + i) * 64 + lane];
      const float wq  = W_ql[i * 64 + lane];
      const float wg0 = W_qg[i * 128 + lane];
      const float wg1 = W_qg[i * 128 + 64 + lane];
      const float4 qv = *(const float4*)&qT[w][i][0];
      s[0]  += qv.x * wn;  s[1]  += qv.y * wn;  s[2]  += qv.z * wn;  s[3]  += qv.w * wn;
      ql[0] += qv.x * wq;  ql[1] += qv.y * wq;  ql[2] += qv.z * wq;  ql[3] += qv.w * wq;
      g0[0] += qv.x * wg0; g0[1] += qv.y * wg0; g0[2] += qv.z * wg0; g0[3] += qv.w * wg0;
      g1[0] += qv.x * wg1; g1[1] += qv.y * wg1; g1[2] += qv.z * wg1; g1[3] += qv.w * wg1;
    }
    const float wn0 = W_nbr[lane], wn1 = W_nbr[64 + lane];
    #pragma unroll
    for (int si = 0; si < 4; ++si) {
      const int n = n0 + si;
      S[n * 64 + lane] = s[si];
      qlocal[n * 64 + lane] = ql[si];
      qg[n * 128 + lane] = g0[si];
      qg[n * 128 + 64 + lane] = g1[si];
      float p0 = wn0 * ql[si], p1 = wn1 * ql[si];
      #pragma unroll
      for (int o = 32; o; o >>= 1) { p0 += __shfl_xor(p0, o); p1 += __shfl_xor(p1, o); }
      if (lane == 0) { c01[2 * n] = p0; c01[2 * n + 1] = p1; }
    }
    const float gl = ln_g[lane];
    #pragma unroll
    for (int si = 0; si < 4; ++si) qT[w][lane][si] = s[si] * gl;
    float sm0 = 0.f, sm1 = 0.f, sm2 = 0.f, sm3 = 0.f;
    #pragma unroll 4
    for (int h = 0; h < 64; ++h) {
      const float w1v = W_m1[h * 64 + lane];
      const float4 sv = *(const float4*)&qT[w][h][0];
      sm0 += sv.x * w1v; sm1 += sv.y * w1v; sm2 += sv.z * w1v; sm3 += sv.w * w1v;
    }
    SS[(n0 + 0) * 64 + lane] = make_float2(s[0], sm0);
    SS[(n0 + 1) * 64 + lane] = make_float2(s[1], sm1);
    SS[(n0 + 2) * 64 + lane] = make_float2(s[2], sm2);
    SS[(n0 + 3) * 64 + lane] = make_float2(s[3], sm3);
  } else if (bid < 173) {
    const int team = tid >> 7, o = tid & 127;
    const int bt = (bid - 149) * 4 + team;
    const int t = bt % NT;
    for (int i = o; i < 1024; i += 128) lat[team][i] = latent[bt * 1024 + i];
    __syncthreads();
    float acc = b_lat[o] + b_lf[o];
    #pragma unroll 8
    for (int i = 0; i < 1024; ++i) acc += lat[team][i] * W_lat[i * 128 + o];
    #pragma unroll
    for (int i = 0; i < 32; ++i) acc += face_emb[t * 32 + i] * W_lf[i * 128 + o];
    kvS[team][o] = acc;
    __syncthreads();
    float kk = b_k[o], vv = b_v[o];
    #pragma unroll 4
    for (int i = 0; i < 128; ++i) {
      const float c = kvS[team][i];
      kk += c * W_k[i * 128 + o];
      vv += c * W_v[i * 128 + o];
    }
    kg[bt * 128 + o] = kk;
    vrow[team][o] = vv;
    __syncthreads();
    #pragma unroll
    for (int h = 0; h < 4; ++h) {
      float a = 0.f;
      #pragma unroll 8
      for (int i = 0; i < 32; ++i)
        a += vrow[team][h * 32 + i] * W_go[(h * 32 + i) * 128 + o];
      vwl[team][h][o] = a;
    }
    __syncthreads();
    if (o < 64) {
      #pragma unroll
      for (int h = 0; h < 4; ++h) {
        float m = 0.f;
        #pragma unroll 4
        for (int i = 0; i < 128; ++i)
          m += vwl[team][h][i] * ln_g[64 + i] * W_m1[(64 + i) * 64 + o];
        TBL[(bt * 4 + h) * 64 + o] =
            make_float4(vwl[team][h][2 * o], vwl[team][h][2 * o + 1], m, 0.f);
      }
    }
  } else {
    const int o = tid;
    if (o < 64) {
      float wa = 0.f, wb = 0.f;
      #pragma unroll 4
      for (int h = 0; h < 64; ++h) {
        const float gw = ln_g[h] * W_m1[h * 64 + o];
        wa += W_nbr[h] * gw;
        wb += W_nbr[64 + h] * gw;
      }
      C[o] = wa; C[64 + o] = wb;
      float g = 0.f, p = 0.f;
      #pragma unroll 4
      for (int d = 0; d < 192; ++d) {
        const float w1 = W_m1[d * 64 + o];
        g += ln_g[d] * w1;
        p += ln_b[d] * w1;
      }
      C[128 + o] = g; C[192 + o] = p + b_m1[o];
      float c1 = 0.f;
      #pragma unroll 4
      for (int i = 0; i < 128; ++i)
        c1 += b_go[i] * ln_g[64 + i] * W_m1[(64 + i) * 64 + o];
      C[256 + o] = c1;
    }
  }
}

// ============ D[n,k] = S[knn[n,k]] . qlocal[n]  (batch-independent) ========
__global__ void precompute_D(const int* __restrict__ knn,
    const float* __restrict__ S, const float* __restrict__ qlocal,
    float* __restrict__ D)
{
  const int idx = blockIdx.x * 256 + threadIdx.x;
  const int n = idx >> 4;
  if (n >= NSN) return;
  const int j = knn[idx];
  const float4* Sr = (const float4*)(S + j * 64);
  const float4* Qr = (const float4*)(qlocal + n * 64);
  float acc = 0.f;
  #pragma unroll 4
  for (int i = 0; i < 16; ++i) {
    const float4 a = Sr[i]; const float4 q = Qr[i];
    acc += a.x * q.x + a.y * q.y + a.z * q.z + a.w * q.w;
  }
  D[idx] = acc;
}

// ============ Per-item precompute: KNN softmax + global-attn weights =======
// thread = item (b,n). ATT[item,16], AX[item]=(sum att*x0, sum att*x1),
// GAW[item*24 + h*6 + t] = softmaxed global attention weight.
__launch_bounds__(256, 2)
__global__ void precompute_item(const int* __restrict__ knn,
    const float* __restrict__ D, const float* __restrict__ c01,
    const float* __restrict__ x_flat, const int* __restrict__ mask,
    const float* __restrict__ qg, const float* __restrict__ kg,
    float* __restrict__ ATT, float2* __restrict__ AX, float* __restrict__ GAW)
{
  const int i = blockIdx.x * 256 + threadIdx.x;
  if (i >= NB * NSN) return;
  const int b = i / NSN;
  const int n = i - b * NSN;

  // ---- KNN attention ----
  int j[16];
  {
    const int4* kr = (const int4*)(knn + n * 16);
    const int4 a = kr[0], bb = kr[1], c = kr[2], d = kr[3];
    j[0]=a.x; j[1]=a.y; j[2]=a.z; j[3]=a.w;
    j[4]=bb.x; j[5]=bb.y; j[6]=bb.z; j[7]=bb.w;
    j[8]=c.x; j[9]=c.y; j[10]=c.z; j[11]=c.w;
    j[12]=d.x; j[13]=d.y; j[14]=d.z; j[15]=d.w;
  }
  float dg[16];
  {
    const float4* dr = (const float4*)(D + n * 16);
    const float4 a = dr[0], bb = dr[1], c = dr[2], d = dr[3];
    dg[0]=a.x; dg[1]=a.y; dg[2]=a.z; dg[3]=a.w;
    dg[4]=bb.x; dg[5]=bb.y; dg[6]=bb.z; dg[7]=bb.w;
    dg[8]=c.x; dg[9]=c.y; dg[10]=c.z; dg[11]=c.w;
    dg[12]=d.x; dg[13]=d.y; dg[14]=d.z; dg[15]=d.w;
  }
  const float2 cv = *(const float2*)(c01 + 2 * n);
  const float* xb = x_flat + (size_t)b * NSN * 2;
  const int* mb = mask + b * NSN;
  float x0[16], x1[16], lg[16];
  #pragma unroll 4
  for (int k = 0; k < 16; ++k) {
    const float2 xv = *(const float2*)(xb + 2 * j[k]);
    const int mk = mb[j[k]];
    x0[k] = xv.x; x1[k] = xv.y;
    const float l = (dg[k] + xv.x * cv.x + xv.y * cv.y) * 0.125f;
    lg[k] = (mk != 0) ? -10000.0f : l;
  }
  float mx = lg[0];
  #pragma unroll
  for (int k = 1; k < 16; ++k) mx = fmaxf(mx, lg[k]);
  float s = 0.f;
  #pragma unroll
  for (int k = 0; k < 16; ++k) { lg[k] = __expf(lg[k] - mx); s += lg[k]; }
  const float inv = 1.0f / s;
  float ax0 = 0.f, ax1 = 0.f;
  #pragma unroll
  for (int k = 0; k < 16; ++k) { lg[k] *= inv; ax0 += lg[k] * x0[k]; ax1 += lg[k] * x1[k]; }
  {
    float4* ao = (float4*)(ATT + (size_t)i * 16);
    ao[0] = make_float4(lg[0], lg[1], lg[2], lg[3]);
    ao[1] = make_float4(lg[4], lg[5], lg[6], lg[7]);
    ao[2] = make_float4(lg[8], lg[9], lg[10], lg[11]);
    ao[3] = make_float4(lg[12], lg[13], lg[14], lg[15]);
    AX[i] = make_float2(ax0, ax1);
  }

  // ---- global attention weights ----
  const float* qgr = qg + n * 128;
  const float* kgb = kg + b * NT * 128;
  #pragma unroll 1
  for (int h = 0; h < 4; ++h) {
    float4 q[8];
    const float4* q4 = (const float4*)(qgr + h * 32);
    #pragma unroll
    for (int u = 0; u < 8; ++u) q[u] = q4[u];
    float p[NT];
    #pragma unroll
    for (int t = 0; t < NT; ++t) {
      const float4* k4 = (const float4*)(kgb + t * 128 + h * 32);
      float a = 0.f;
      #pragma unroll
      for (int u = 0; u < 8; ++u) {
        const float4 kv = k4[u];
        a += q[u].x * kv.x + q[u].y * kv.y + q[u].z * kv.z + q[u].w * kv.w;
      }
      p[t] = a * 0.17677669529663687f;   // 1/sqrt(32)
    }
    float m2 = p[0];
    #pragma unroll
    for (int t = 1; t < NT; ++t) m2 = fmaxf(m2, p[t]);
    float s2 = 0.f;
    #pragma unroll
    for (int t = 0; t < NT; ++t) { p[t] = __expf(p[t] - m2); s2 += p[t]; }
    const float i2 = 1.0f / s2;
    float* go = GAW + (size_t)i * 24 + h * 6;
    #pragma unroll
    for (int t = 0; t < NT; ++t) go[t] = p[t] * i2;
  }
}

// ============ Main fused kernel: one wave per (b,n), pure accumulation =====
__launch_bounds__(512, 2)
__global__ void fused_main(const int* __restrict__ mask,
    const int* __restrict__ knn, const float* __restrict__ Wnbr,
    const float2* __restrict__ SS, const float* __restrict__ ATT,
    const float2* __restrict__ AX, const float* __restrict__ GAW,
    const float4* __restrict__ TBL, const float* __restrict__ CONSTS,
    const float* __restrict__ bgo, const float* __restrict__ Wm2,
    const float* __restrict__ bm2, float* __restrict__ out)
{
  __shared__ __align__(16) float4 TBLl[NT * 4 * 64];  // 24 KB

  const int tid = threadIdx.x;
  const int b = blockIdx.x / NGB;
  const int ng = blockIdx.x - b * NGB;
  {
    const float4* tb = TBL + b * (NT * 4 * 64);
    for (int i = tid; i < NT * 4 * 64; i += 512) TBLl[i] = tb[i];
  }
  __syncthreads();

  const int w = tid >> 6, lane = tid & 63;
  const int n = ng * 8 + w;
  const int item = b * NSN + n;

  const float wa  = CONSTS[lane],       wbc = CONSTS[64 + lane];
  const float cg  = CONSTS[128 + lane], cp  = CONSTS[192 + lane];
  const float cc1 = CONSTS[256 + lane];
  const float w0 = Wnbr[lane], w1 = Wnbr[64 + lane];
  const float2 bgov = *(const float2*)(bgo + 2 * lane);
  const float wm2 = Wm2[lane], bm2s = bm2[0];
  const int mself = mask[item];

  int jv = 0; float aw = 0.f;
  if (lane < 16) {
    jv = knn[n * 16 + lane];
    aw = ATT[(size_t)item * 16 + lane];
  }
  float gw = 0.f;
  if (lane < 24) gw = GAW[(size_t)item * 24 + lane];
  const float2 axv = AX[item];

  // ---- lf (lane=h) and L (lane=o): 16 packed float2 gathers, 4-batched ----
  float lf = axv.x * w0 + axv.y * w1;
  float L  = axv.x * wa + axv.y * wbc;
  #pragma unroll
  for (int kb = 0; kb < 4; ++kb) {
    const int j0 = __builtin_amdgcn_readlane(jv, 4 * kb + 0);
    const int j1 = __builtin_amdgcn_readlane(jv, 4 * kb + 1);
    const int j2 = __builtin_amdgcn_readlane(jv, 4 * kb + 2);
    const int j3 = __builtin_amdgcn_readlane(jv, 4 * kb + 3);
    const float a0 = rl_f(aw, 4 * kb + 0);
    const float a1 = rl_f(aw, 4 * kb + 1);
    const float a2 = rl_f(aw, 4 * kb + 2);
    const float a3 = rl_f(aw, 4 * kb + 3);
    const float2 s0 = SS[j0 * 64 + lane];
    const float2 s1 = SS[j1 * 64 + lane];
    const float2 s2 = SS[j2 * 64 + lane];
    const float2 s3 = SS[j3 * 64 + lane];
    lf += a0 * s0.x + a1 * s1.x + a2 * s2.x + a3 * s3.x;
    L  += a0 * s0.y + a1 * s1.y + a2 * s2.y + a3 * s3.y;
  }

  // ---- g_out + M from packed table with precomputed weights ----
  float g0 = bgov.x, g1 = bgov.y, M = 0.f;
  #pragma unroll 2
  for (int t = 0; t < NT; ++t) {
    const float4 r0 = TBLl[(t * 4 + 0) * 64 + lane];
    const float4 r1 = TBLl[(t * 4 + 1) * 64 + lane];
    const float4 r2 = TBLl[(t * 4 + 2) * 64 + lane];
    const float4 r3 = TBLl[(t * 4 + 3) * 64 + lane];
    const float a0 = rl_f(gw, t);
    const float a1 = rl_f(gw, 6 + t);
    const float a2 = rl_f(gw, 12 + t);
    const float a3 = rl_f(gw, 18 + t);
    g0 += a0 * r0.x + a1 * r1.x + a2 * r2.x + a3 * r3.x;
    g1 += a0 * r0.y + a1 * r1.y + a2 * r2.y + a3 * r3.y;
    M  += a0 * r0.z + a1 * r1.z + a2 * r2.z + a3 * r3.z;
  }

  // ---- LayerNorm stats over 192 ----
  float s1 = lf + g0 + g1;
  float s2 = lf * lf + g0 * g0 + g1 * g1;
  #pragma unroll
  for (int o = 32; o; o >>= 1) { s1 += __shfl_xor(s1, o); s2 += __shfl_xor(s2, o); }
  const float mu  = s1 * (1.0f / 192.0f);
  const float var = s2 * (1.0f / 192.0f) - mu * mu;
  const float rinv = rsqrtf(var + 1e-5f);

  // ---- folded MLP ----
  const float m1 = rinv * (L + M + cc1 - mu * cg) + cp;
  const float gelu = 0.5f * m1 * (1.0f + erff(m1 * 0.7071067811865476f));
  float pr = gelu * wm2;
  #pragma unroll
  for (int o = 32; o; o >>= 1) pr += __shfl_xor(pr, o);
  float res = pr + bm2s;
  if (mself == 0) res = 0.f;
  if (lane == 0) out[item] = res;
}

extern "C" void kernel_launch(void* const* d_in, const int* in_sizes, int n_in,
                              void* d_out, int out_size, void* d_ws, size_t ws_size,
                              hipStream_t stream) {
  (void)in_sizes; (void)n_in; (void)out_size; (void)ws_size;
  const float* x_flat   = (const float*)d_in[0];
  const float* latent   = (const float*)d_in[1];
  const float* pos_emb  = (const float*)d_in[2];
  const float* face_emb = (const float*)d_in[3];
  const float* W_nbr = (const float*)d_in[4];
  const float* b_nbr = (const float*)d_in[5];
  const float* W_ql  = (const float*)d_in[6];
  const float* b_ql  = (const float*)d_in[7];
  const float* W_lat = (const float*)d_in[8];
  const float* b_lat = (const float*)d_in[9];
  const float* W_lf  = (const float*)d_in[10];
  const float* b_lf  = (const float*)d_in[11];
  const float* W_qg  = (const float*)d_in[12];
  const float* b_qg  = (const float*)d_in[13];
  const float* W_k   = (const float*)d_in[14];
  const float* b_k   = (const float*)d_in[15];
  const float* W_v   = (const float*)d_in[16];
  const float* b_v   = (const float*)d_in[17];
  const float* W_go  = (const float*)d_in[18];
  const float* b_go  = (const float*)d_in[19];
  const float* ln_g  = (const float*)d_in[20];
  const float* ln_b  = (const float*)d_in[21];
  const float* W_m1  = (const float*)d_in[22];
  const float* b_m1  = (const float*)d_in[23];
  const float* W_m2  = (const float*)d_in[24];
  const float* b_m2  = (const float*)d_in[25];
  const int* mask     = (const int*)d_in[26];
  const int* knn      = (const int*)d_in[27];
  const int* face_ids = (const int*)d_in[28];
  float* out = (float*)d_out;

  float* ws = (float*)d_ws;
  float* S      = ws;  ws += NSN * 64;
  float* qlocal = ws;  ws += NSN * 64;
  float* qgb    = ws;  ws += NSN * 128;
  float* c01    = ws;  ws += NSN * 2;
  float2* SSt   = (float2*)ws;  ws += NSN * 64 * 2;
  float* kgb    = ws;  ws += NB * NT * 128;
  float4* TBLt  = (float4*)ws;  ws += NB * NT * 4 * 64 * 4;
  float* CONSTS = ws;  ws += 5 * 64;
  float* Dt     = ws;  ws += NSN * KNN;
  float* ATTt   = ws;  ws += NB * NSN * KNN;
  float2* AXt   = (float2*)ws;  ws += NB * NSN * 2;
  float* GAWt   = ws;  ws += NB * NSN * 24;

  precompute_all<<<174, 512, 0, stream>>>(pos_emb, face_emb, face_ids,
      W_nbr, b_nbr, W_ql, b_ql, W_qg, b_qg,
      latent, W_lat, b_lat, W_lf, b_lf, W_k, b_k, W_v, b_v,
      W_go, b_go, W_m1, b_m1, ln_g, ln_b,
      S, qlocal, qgb, c01, SSt, kgb, TBLt, CONSTS);
  precompute_D<<<(NSN * KNN + 255) / 256, 256, 0, stream>>>(knn, S, qlocal, Dt);
  precompute_item<<<(NB * NSN + 255) / 256, 256, 0, stream>>>(knn, Dt, c01,
      x_flat, mask, qgb, kgb, ATTt, AXt, GAWt);
  fused_main<<<NB * NGB, 512, 0, stream>>>(mask, knn, W_nbr,
      SSt, ATTt, AXt, GAWt, TBLt, CONSTS, b_go, W_m2, b_m2, out);
}

// Round 12
// 269.858 us; speedup vs baseline: 1.5267x; 1.1011x over previous
//
#include <hip/hip_runtime.h>
#include <math.h>

#define NSN 4760
#define KNN 16
#define NT 6
#define NB 16
#define NGB 595    // n-groups per batch: 595*8 = 4760

__device__ __forceinline__ float rl_f(float v, int lane) {
  return __builtin_bit_cast(float, __builtin_amdgcn_readlane(__builtin_bit_cast(int, v), lane));
}

// ============ Merged precompute ============================================
// bid <  595 : sensor — 1 sensor per wave (4760 waves)
// bid <  691 : latent — 1 (b,t) per 512-thread block, K-split partials
// bid == 691 : folded constants
__global__ void precompute_all(const float* __restrict__ pos_emb,
    const float* __restrict__ face_emb, const int* __restrict__ face_ids,
    const float* __restrict__ W_nbr, const float* __restrict__ b_nbr,
    const float* __restrict__ W_ql, const float* __restrict__ b_ql,
    const float* __restrict__ W_qg, const float* __restrict__ b_qg,
    const float* __restrict__ latent,
    const float* __restrict__ W_lat, const float* __restrict__ b_lat,
    const float* __restrict__ W_lf, const float* __restrict__ b_lf,
    const float* __restrict__ W_k, const float* __restrict__ b_k,
    const float* __restrict__ W_v, const float* __restrict__ b_v,
    const float* __restrict__ W_go, const float* __restrict__ b_go,
    const float* __restrict__ W_m1, const float* __restrict__ b_m1,
    const float* __restrict__ ln_g, const float* __restrict__ ln_b,
    float* __restrict__ S, float* __restrict__ qlocal,
    float* __restrict__ qg, float* __restrict__ c01, float2* __restrict__ SS,
    float* __restrict__ kg, float4* __restrict__ TBL, float* __restrict__ C)
{
  __shared__ __align__(16) float qL[8][128];     // sensor: 4 KB
  __shared__ __align__(16) float lat[1024];      // latent: 4 KB
  __shared__ __align__(16) float part[4][128];   // 2 KB
  __shared__ __align__(16) float kvS[128];
  __shared__ __align__(16) float vrow[128];
  __shared__ __align__(16) float vwl[4][128];    // 2 KB
  __shared__ __align__(16) float ghl[128];
  const int bid = blockIdx.x;
  const int tid = threadIdx.x;

  if (bid < 595) {
    // ---------------- sensor: wave = one sensor ----------------
    const int w = tid >> 6, lane = tid & 63;
    const int n = bid * 8 + w;
    const int fid = face_ids[n];
    const int e1 = lane + 64;
    qL[w][lane] = pos_emb[n * 96 + lane];
    qL[w][e1] = (e1 < 96) ? pos_emb[n * 96 + e1] : face_emb[fid * 32 + (e1 - 96)];
    float s  = b_nbr[lane], ql = b_ql[lane];
    float g0 = b_qg[lane],  g1 = b_qg[lane + 64];
    #pragma unroll 2
    for (int i = 0; i < 128; ++i) {
      const float qi = qL[w][i];
      s  += qi * W_nbr[(2 + i) * 64 + lane];
      ql += qi * W_ql[i * 64 + lane];
      g0 += qi * W_qg[i * 128 + lane];
      g1 += qi * W_qg[i * 128 + 64 + lane];
    }
    S[n * 64 + lane] = s;
    qlocal[n * 64 + lane] = ql;
    qg[n * 128 + lane] = g0;
    qg[n * 128 + 64 + lane] = g1;
    float p0 = W_nbr[lane] * ql, p1 = W_nbr[64 + lane] * ql;
    #pragma unroll
    for (int o = 32; o; o >>= 1) { p0 += __shfl_xor(p0, o); p1 += __shfl_xor(p1, o); }
    if (lane == 0) { c01[2 * n] = p0; c01[2 * n + 1] = p1; }
    // SM = (S .* ln_g[:64]) @ W_m1[:64,:]
    qL[w][lane] = s * ln_g[lane];
    float sm = 0.f;
    #pragma unroll 2
    for (int h = 0; h < 64; ++h) {
      sm += qL[w][h] * W_m1[h * 64 + lane];
    }
    SS[n * 64 + lane] = make_float2(s, sm);
  } else if (bid < 691) {
    // ---------------- latent: block = one (b,t) ----------------
    const int bt = bid - 595;
    const int t = bt % NT;
    const int chunk = tid >> 7, o = tid & 127;
    for (int i = tid; i < 1024; i += 512) lat[i] = latent[bt * 1024 + i];
    if (tid < 128) ghl[tid] = ln_g[64 + tid];
    __syncthreads();
    // kv: 1024-dot split into 4 chunks of 256
    {
      float acc = 0.f;
      const int i0 = chunk * 256;
      #pragma unroll 4
      for (int i = 0; i < 256; ++i)
        acc += lat[i0 + i] * W_lat[(i0 + i) * 128 + o];
      part[chunk][o] = acc;
    }
    __syncthreads();
    if (tid < 128) {
      float acc = part[0][o] + part[1][o] + part[2][o] + part[3][o]
                + b_lat[o] + b_lf[o];
      #pragma unroll
      for (int i = 0; i < 32; ++i) acc += face_emb[t * 32 + i] * W_lf[i * 128 + o];
      kvS[o] = acc;
    }
    __syncthreads();
    // kg and vrow: 128-dots split into 2 chunks; roles 0/1 -> W_k, 2/3 -> W_v
    {
      const float* Wx = (chunk < 2) ? W_k : W_v;
      const int i0 = (chunk & 1) * 64;
      float acc = 0.f;
      #pragma unroll 4
      for (int i = 0; i < 64; ++i)
        acc += kvS[i0 + i] * Wx[(i0 + i) * 128 + o];
      part[chunk][o] = acc;
    }
    __syncthreads();
    if (tid < 128) {
      kg[bt * 128 + o] = part[0][o] + part[1][o] + b_k[o];
    } else if (tid < 256) {
      vrow[o] = part[2][o] + part[3][o] + b_v[o];
    }
    __syncthreads();
    // VW: 512 outputs = 1 per thread (h = chunk)
    {
      float a = 0.f;
      #pragma unroll 8
      for (int i = 0; i < 32; ++i)
        a += vrow[chunk * 32 + i] * W_go[(chunk * 32 + i) * 128 + o];
      vwl[chunk][o] = a;
    }
    __syncthreads();
    // VWM + TBL pack: 256 outputs (4h x 64o)
    if (tid < 256) {
      const int h = tid >> 6, oo = tid & 63;
      float m = 0.f;
      #pragma unroll 4
      for (int i = 0; i < 128; ++i)
        m += vwl[h][i] * ghl[i] * W_m1[(64 + i) * 64 + oo];
      TBL[(bt * 4 + h) * 64 + oo] =
          make_float4(vwl[h][2 * oo], vwl[h][2 * oo + 1], m, 0.f);
    }
  } else {
    // ---------------- consts ----------------
    const int o = tid;
    if (o < 64) {
      float wa = 0.f, wb = 0.f;
      #pragma unroll 4
      for (int h = 0; h < 64; ++h) {
        const float gw = ln_g[h] * W_m1[h * 64 + o];
        wa += W_nbr[h] * gw;
        wb += W_nbr[64 + h] * gw;
      }
      C[o] = wa; C[64 + o] = wb;
      float g = 0.f, p = 0.f;
      #pragma unroll 4
      for (int d = 0; d < 192; ++d) {
        const float w1 = W_m1[d * 64 + o];
        g += ln_g[d] * w1;
        p += ln_b[d] * w1;
      }
      C[128 + o] = g; C[192 + o] = p + b_m1[o];
      float c1 = 0.f;
      #pragma unroll 4
      for (int i = 0; i < 128; ++i)
        c1 += b_go[i] * ln_g[64 + i] * W_m1[(64 + i) * 64 + o];
      C[256 + o] = c1;
    }
  }
}

// ============ D[n,k] = S[knn[n,k]] . qlocal[n]  (batch-independent) ========
__global__ void precompute_D(const int* __restrict__ knn,
    const float* __restrict__ S, const float* __restrict__ qlocal,
    float* __restrict__ D)
{
  const int idx = blockIdx.x * 256 + threadIdx.x;
  const int n = idx >> 4;
  if (n >= NSN) return;
  const int j = knn[idx];
  const float4* Sr = (const float4*)(S + j * 64);
  const float4* Qr = (const float4*)(qlocal + n * 64);
  float acc = 0.f;
  #pragma unroll 4
  for (int i = 0; i < 16; ++i) {
    const float4 a = Sr[i]; const float4 q = Qr[i];
    acc += a.x * q.x + a.y * q.y + a.z * q.z + a.w * q.w;
  }
  D[idx] = acc;
}

// ============ Per-item precompute: KNN softmax + global-attn weights =======
__launch_bounds__(256, 2)
__global__ void precompute_item(const int* __restrict__ knn,
    const float* __restrict__ D, const float* __restrict__ c01,
    const float* __restrict__ x_flat, const int* __restrict__ mask,
    const float* __restrict__ qg, const float* __restrict__ kg,
    float* __restrict__ ATT, float2* __restrict__ AX, float* __restrict__ GAW)
{
  const int i = blockIdx.x * 256 + threadIdx.x;
  if (i >= NB * NSN) return;
  const int b = i / NSN;
  const int n = i - b * NSN;

  // ---- KNN attention ----
  int j[16];
  {
    const int4* kr = (const int4*)(knn + n * 16);
    const int4 a = kr[0], bb = kr[1], c = kr[2], d = kr[3];
    j[0]=a.x; j[1]=a.y; j[2]=a.z; j[3]=a.w;
    j[4]=bb.x; j[5]=bb.y; j[6]=bb.z; j[7]=bb.w;
    j[8]=c.x; j[9]=c.y; j[10]=c.z; j[11]=c.w;
    j[12]=d.x; j[13]=d.y; j[14]=d.z; j[15]=d.w;
  }
  float dg[16];
  {
    const float4* dr = (const float4*)(D + n * 16);
    const float4 a = dr[0], bb = dr[1], c = dr[2], d = dr[3];
    dg[0]=a.x; dg[1]=a.y; dg[2]=a.z; dg[3]=a.w;
    dg[4]=bb.x; dg[5]=bb.y; dg[6]=bb.z; dg[7]=bb.w;
    dg[8]=c.x; dg[9]=c.y; dg[10]=c.z; dg[11]=c.w;
    dg[12]=d.x; dg[13]=d.y; dg[14]=d.z; dg[15]=d.w;
  }
  const float2 cv = *(const float2*)(c01 + 2 * n);
  const float* xb = x_flat + (size_t)b * NSN * 2;
  const int* mb = mask + b * NSN;
  float x0[16], x1[16], lg[16];
  #pragma unroll 4
  for (int k = 0; k < 16; ++k) {
    const float2 xv = *(const float2*)(xb + 2 * j[k]);
    const int mk = mb[j[k]];
    x0[k] = xv.x; x1[k] = xv.y;
    const float l = (dg[k] + xv.x * cv.x + xv.y * cv.y) * 0.125f;
    lg[k] = (mk != 0) ? -10000.0f : l;
  }
  float mx = lg[0];
  #pragma unroll
  for (int k = 1; k < 16; ++k) mx = fmaxf(mx, lg[k]);
  float s = 0.f;
  #pragma unroll
  for (int k = 0; k < 16; ++k) { lg[k] = __expf(lg[k] - mx); s += lg[k]; }
  const float inv = 1.0f / s;
  float ax0 = 0.f, ax1 = 0.f;
  #pragma unroll
  for (int k = 0; k < 16; ++k) { lg[k] *= inv; ax0 += lg[k] * x0[k]; ax1 += lg[k] * x1[k]; }
  {
    float4* ao = (float4*)(ATT + (size_t)i * 16);
    ao[0] = make_float4(lg[0], lg[1], lg[2], lg[3]);
    ao[1] = make_float4(lg[4], lg[5], lg[6], lg[7]);
    ao[2] = make_float4(lg[8], lg[9], lg[10], lg[11]);
    ao[3] = make_float4(lg[12], lg[13], lg[14], lg[15]);
    AX[i] = make_float2(ax0, ax1);
  }

  // ---- global attention weights ----
  const float* qgr = qg + n * 128;
  const float* kgb = kg + b * NT * 128;
  #pragma unroll 1
  for (int h = 0; h < 4; ++h) {
    float4 q[8];
    const float4* q4 = (const float4*)(qgr + h * 32);
    #pragma unroll
    for (int u = 0; u < 8; ++u) q[u] = q4[u];
    float p[NT];
    #pragma unroll
    for (int t = 0; t < NT; ++t) {
      const float4* k4 = (const float4*)(kgb + t * 128 + h * 32);
      float a = 0.f;
      #pragma unroll
      for (int u = 0; u < 8; ++u) {
        const float4 kv = k4[u];
        a += q[u].x * kv.x + q[u].y * kv.y + q[u].z * kv.z + q[u].w * kv.w;
      }
      p[t] = a * 0.17677669529663687f;   // 1/sqrt(32)
    }
    float m2 = p[0];
    #pragma unroll
    for (int t = 1; t < NT; ++t) m2 = fmaxf(m2, p[t]);
    float s2 = 0.f;
    #pragma unroll
    for (int t = 0; t < NT; ++t) { p[t] = __expf(p[t] - m2); s2 += p[t]; }
    const float i2 = 1.0f / s2;
    float* go = GAW + (size_t)i * 24 + h * 6;
    #pragma unroll
    for (int t = 0; t < NT; ++t) go[t] = p[t] * i2;
  }
}

// ============ Main fused kernel: one wave per (b,n), pure accumulation =====
// (512,4): VGPR cap 64 (natural ~44, no spill), 4 blocks/CU x 24KB LDS = 96KB
__launch_bounds__(512, 4)
__global__ void fused_main(const int* __restrict__ mask,
    const int* __restrict__ knn, const float* __restrict__ Wnbr,
    const float2* __restrict__ SS, const float* __restrict__ ATT,
    const float2* __restrict__ AX, const float* __restrict__ GAW,
    const float4* __restrict__ TBL, const float* __restrict__ CONSTS,
    const float* __restrict__ bgo, const float* __restrict__ Wm2,
    const float* __restrict__ bm2, float* __restrict__ out)
{
  __shared__ __align__(16) float4 TBLl[NT * 4 * 64];  // 24 KB

  const int tid = threadIdx.x;
  const int b = blockIdx.x / NGB;
  const int ng = blockIdx.x - b * NGB;
  {
    const float4* tb = TBL + b * (NT * 4 * 64);
    for (int i = tid; i < NT * 4 * 64; i += 512) TBLl[i] = tb[i];
  }
  __syncthreads();

  const int w = tid >> 6, lane = tid & 63;
  const int n = ng * 8 + w;
  const int item = b * NSN + n;

  const float wa  = CONSTS[lane],       wbc = CONSTS[64 + lane];
  const float cg  = CONSTS[128 + lane], cp  = CONSTS[192 + lane];
  const float cc1 = CONSTS[256 + lane];
  const float w0 = Wnbr[lane], w1 = Wnbr[64 + lane];
  const float2 bgov = *(const float2*)(bgo + 2 * lane);
  const float wm2 = Wm2[lane], bm2s = bm2[0];
  const int mself = mask[item];

  int jv = 0; float aw = 0.f;
  if (lane < 16) {
    jv = knn[n * 16 + lane];
    aw = ATT[(size_t)item * 16 + lane];
  }
  float gw = 0.f;
  if (lane < 24) gw = GAW[(size_t)item * 24 + lane];
  const float2 axv = AX[item];

  // ---- lf (lane=h) and L (lane=o): 16 packed float2 gathers, 4-batched ----
  float lf = axv.x * w0 + axv.y * w1;
  float L  = axv.x * wa + axv.y * wbc;
  #pragma unroll
  for (int kb = 0; kb < 4; ++kb) {
    const int j0 = __builtin_amdgcn_readlane(jv, 4 * kb + 0);
    const int j1 = __builtin_amdgcn_readlane(jv, 4 * kb + 1);
    const int j2 = __builtin_amdgcn_readlane(jv, 4 * kb + 2);
    const int j3 = __builtin_amdgcn_readlane(jv, 4 * kb + 3);
    const float a0 = rl_f(aw, 4 * kb + 0);
    const float a1 = rl_f(aw, 4 * kb + 1);
    const float a2 = rl_f(aw, 4 * kb + 2);
    const float a3 = rl_f(aw, 4 * kb + 3);
    const float2 s0 = SS[j0 * 64 + lane];
    const float2 s1 = SS[j1 * 64 + lane];
    const float2 s2 = SS[j2 * 64 + lane];
    const float2 s3 = SS[j3 * 64 + lane];
    lf += a0 * s0.x + a1 * s1.x + a2 * s2.x + a3 * s3.x;
    L  += a0 * s0.y + a1 * s1.y + a2 * s2.y + a3 * s3.y;
  }

  // ---- g_out + M from packed table with precomputed weights ----
  float g0 = bgov.x, g1 = bgov.y, M = 0.f;
  #pragma unroll 2
  for (int t = 0; t < NT; ++t) {
    const float4 r0 = TBLl[(t * 4 + 0) * 64 + lane];
    const float4 r1 = TBLl[(t * 4 + 1) * 64 + lane];
    const float4 r2 = TBLl[(t * 4 + 2) * 64 + lane];
    const float4 r3 = TBLl[(t * 4 + 3) * 64 + lane];
    const float a0 = rl_f(gw, t);
    const float a1 = rl_f(gw, 6 + t);
    const float a2 = rl_f(gw, 12 + t);
    const float a3 = rl_f(gw, 18 + t);
    g0 += a0 * r0.x + a1 * r1.x + a2 * r2.x + a3 * r3.x;
    g1 += a0 * r0.y + a1 * r1.y + a2 * r2.y + a3 * r3.y;
    M  += a0 * r0.z + a1 * r1.z + a2 * r2.z + a3 * r3.z;
  }

  // ---- LayerNorm stats over 192 ----
  float s1 = lf + g0 + g1;
  float s2 = lf * lf + g0 * g0 + g1 * g1;
  #pragma unroll
  for (int o = 32; o; o >>= 1) { s1 += __shfl_xor(s1, o); s2 += __shfl_xor(s2, o); }
  const float mu  = s1 * (1.0f / 192.0f);
  const float var = s2 * (1.0f / 192.0f) - mu * mu;
  const float rinv = rsqrtf(var + 1e-5f);

  // ---- folded MLP ----
  const float m1 = rinv * (L + M + cc1 - mu * cg) + cp;
  const float gelu = 0.5f * m1 * (1.0f + erff(m1 * 0.7071067811865476f));
  float pr = gelu * wm2;
  #pragma unroll
  for (int o = 32; o; o >>= 1) pr += __shfl_xor(pr, o);
  float res = pr + bm2s;
  if (mself == 0) res = 0.f;
  if (lane == 0) out[item] = res;
}

extern "C" void kernel_launch(void* const* d_in, const int* in_sizes, int n_in,
                              void* d_out, int out_size, void* d_ws, size_t ws_size,
                              hipStream_t stream) {
  (void)in_sizes; (void)n_in; (void)out_size; (void)ws_size;
  const float* x_flat   = (const float*)d_in[0];
  const float* latent   = (const float*)d_in[1];
  const float* pos_emb  = (const float*)d_in[2];
  const float* face_emb = (const float*)d_in[3];
  const float* W_nbr = (const float*)d_in[4];
  const float* b_nbr = (const float*)d_in[5];
  const float* W_ql  = (const float*)d_in[6];
  const float* b_ql  = (const float*)d_in[7];
  const float* W_lat = (const float*)d_in[8];
  const float* b_lat = (const float*)d_in[9];
  const float* W_lf  = (const float*)d_in[10];
  const float* b_lf  = (const float*)d_in[11];
  const float* W_qg  = (const float*)d_in[12];
  const float* b_qg  = (const float*)d_in[13];
  const float* W_k   = (const float*)d_in[14];
  const float* b_k   = (const float*)d_in[15];
  const float* W_v   = (const float*)d_in[16];
  const float* b_v   = (const float*)d_in[17];
  const float* W_go  = (const float*)d_in[18];
  const float* b_go  = (const float*)d_in[19];
  const float* ln_g  = (const float*)d_in[20];
  const float* ln_b  = (const float*)d_in[21];
  const float* W_m1  = (const float*)d_in[22];
  const float* b_m1  = (const float*)d_in[23];
  const float* W_m2  = (const float*)d_in[24];
  const float* b_m2  = (const float*)d_in[25];
  const int* mask     = (const int*)d_in[26];
  const int* knn      = (const int*)d_in[27];
  const int* face_ids = (const int*)d_in[28];
  float* out = (float*)d_out;

  float* ws = (float*)d_ws;
  float* S      = ws;  ws += NSN * 64;
  float* qlocal = ws;  ws += NSN * 64;
  float* qgb    = ws;  ws += NSN * 128;
  float* c01    = ws;  ws += NSN * 2;
  float2* SSt   = (float2*)ws;  ws += NSN * 64 * 2;
  float* kgb    = ws;  ws += NB * NT * 128;
  float4* TBLt  = (float4*)ws;  ws += NB * NT * 4 * 64 * 4;
  float* CONSTS = ws;  ws += 5 * 64;
  float* Dt     = ws;  ws += NSN * KNN;
  float* ATTt   = ws;  ws += NB * NSN * KNN;
  float2* AXt   = (float2*)ws;  ws += NB * NSN * 2;
  float* GAWt   = ws;  ws += NB * NSN * 24;

  precompute_all<<<692, 512, 0, stream>>>(pos_emb, face_emb, face_ids,
      W_nbr, b_nbr, W_ql, b_ql, W_qg, b_qg,
      latent, W_lat, b_lat, W_lf, b_lf, W_k, b_k, W_v, b_v,
      W_go, b_go, W_m1, b_m1, ln_g, ln_b,
      S, qlocal, qgb, c01, SSt, kgb, TBLt, CONSTS);
  precompute_D<<<(NSN * KNN + 255) / 256, 256, 0, stream>>>(knn, S, qlocal, Dt);
  precompute_item<<<(NB * NSN + 255) / 256, 256, 0, stream>>>(knn, Dt, c01,
      x_flat, mask, qgb, kgb, ATTt, AXt, GAWt);
  fused_main<<<NB * NGB, 512, 0, stream>>>(mask, knn, W_nbr,
      SSt, ATTt, AXt, GAWt, TBLt, CONSTS, b_go, W_m2, b_m2, out);
}

// Round 13
// 259.216 us; speedup vs baseline: 1.5894x; 1.0411x over previous
//
#include <hip/hip_runtime.h>
#include <math.h>

#define NSN 4760
#define KNN 16
#define NT 6
#define NB 16
#define NGB 595    // n-groups per batch: 595*8 = 4760
#define NBLK 85    // fused blocks per batch: 85 * 7 = 595

__device__ __forceinline__ float rl_f(float v, int lane) {
  return __builtin_bit_cast(float, __builtin_amdgcn_readlane(__builtin_bit_cast(int, v), lane));
}

// ============ Merged precompute ============================================
// bid <  595 : sensor — 1 sensor per wave (4760 waves)
// bid <  691 : latent — 1 (b,t) per 512-thread block, K-split partials
// bid == 691 : folded constants
__global__ void precompute_all(const float* __restrict__ pos_emb,
    const float* __restrict__ face_emb, const int* __restrict__ face_ids,
    const float* __restrict__ W_nbr, const float* __restrict__ b_nbr,
    const float* __restrict__ W_ql, const float* __restrict__ b_ql,
    const float* __restrict__ W_qg, const float* __restrict__ b_qg,
    const float* __restrict__ latent,
    const float* __restrict__ W_lat, const float* __restrict__ b_lat,
    const float* __restrict__ W_lf, const float* __restrict__ b_lf,
    const float* __restrict__ W_k, const float* __restrict__ b_k,
    const float* __restrict__ W_v, const float* __restrict__ b_v,
    const float* __restrict__ W_go, const float* __restrict__ b_go,
    const float* __restrict__ W_m1, const float* __restrict__ b_m1,
    const float* __restrict__ ln_g, const float* __restrict__ ln_b,
    float* __restrict__ S, float* __restrict__ qlocal,
    float* __restrict__ qg, float* __restrict__ c01, float2* __restrict__ SS,
    float* __restrict__ kg, float4* __restrict__ TBL, float* __restrict__ C)
{
  __shared__ __align__(16) float qL[8][128];     // sensor: 4 KB
  __shared__ __align__(16) float lat[1024];      // latent: 4 KB
  __shared__ __align__(16) float part[4][128];   // 2 KB
  __shared__ __align__(16) float kvS[128];
  __shared__ __align__(16) float vrow[128];
  __shared__ __align__(16) float vwl[4][128];    // 2 KB
  __shared__ __align__(16) float ghl[128];
  const int bid = blockIdx.x;
  const int tid = threadIdx.x;

  if (bid < 595) {
    // ---------------- sensor: wave = one sensor ----------------
    const int w = tid >> 6, lane = tid & 63;
    const int n = bid * 8 + w;
    const int fid = face_ids[n];
    const int e1 = lane + 64;
    qL[w][lane] = pos_emb[n * 96 + lane];
    qL[w][e1] = (e1 < 96) ? pos_emb[n * 96 + e1] : face_emb[fid * 32 + (e1 - 96)];
    float s  = b_nbr[lane], ql = b_ql[lane];
    float g0 = b_qg[lane],  g1 = b_qg[lane + 64];
    #pragma unroll 2
    for (int i = 0; i < 128; ++i) {
      const float qi = qL[w][i];
      s  += qi * W_nbr[(2 + i) * 64 + lane];
      ql += qi * W_ql[i * 64 + lane];
      g0 += qi * W_qg[i * 128 + lane];
      g1 += qi * W_qg[i * 128 + 64 + lane];
    }
    S[n * 64 + lane] = s;
    qlocal[n * 64 + lane] = ql;
    qg[n * 128 + lane] = g0;
    qg[n * 128 + 64 + lane] = g1;
    float p0 = W_nbr[lane] * ql, p1 = W_nbr[64 + lane] * ql;
    #pragma unroll
    for (int o = 32; o; o >>= 1) { p0 += __shfl_xor(p0, o); p1 += __shfl_xor(p1, o); }
    if (lane == 0) { c01[2 * n] = p0; c01[2 * n + 1] = p1; }
    // SM = (S .* ln_g[:64]) @ W_m1[:64,:]
    qL[w][lane] = s * ln_g[lane];
    float sm = 0.f;
    #pragma unroll 2
    for (int h = 0; h < 64; ++h) {
      sm += qL[w][h] * W_m1[h * 64 + lane];
    }
    SS[n * 64 + lane] = make_float2(s, sm);
  } else if (bid < 691) {
    // ---------------- latent: block = one (b,t) ----------------
    const int bt = bid - 595;
    const int t = bt % NT;
    const int chunk = tid >> 7, o = tid & 127;
    for (int i = tid; i < 1024; i += 512) lat[i] = latent[bt * 1024 + i];
    if (tid < 128) ghl[tid] = ln_g[64 + tid];
    __syncthreads();
    // kv: 1024-dot split into 4 chunks of 256
    {
      float acc = 0.f;
      const int i0 = chunk * 256;
      #pragma unroll 4
      for (int i = 0; i < 256; ++i)
        acc += lat[i0 + i] * W_lat[(i0 + i) * 128 + o];
      part[chunk][o] = acc;
    }
    __syncthreads();
    if (tid < 128) {
      float acc = part[0][o] + part[1][o] + part[2][o] + part[3][o]
                + b_lat[o] + b_lf[o];
      #pragma unroll
      for (int i = 0; i < 32; ++i) acc += face_emb[t * 32 + i] * W_lf[i * 128 + o];
      kvS[o] = acc;
    }
    __syncthreads();
    // kg and vrow: 128-dots split into 2 chunks; roles 0/1 -> W_k, 2/3 -> W_v
    {
      const float* Wx = (chunk < 2) ? W_k : W_v;
      const int i0 = (chunk & 1) * 64;
      float acc = 0.f;
      #pragma unroll 4
      for (int i = 0; i < 64; ++i)
        acc += kvS[i0 + i] * Wx[(i0 + i) * 128 + o];
      part[chunk][o] = acc;
    }
    __syncthreads();
    if (tid < 128) {
      kg[bt * 128 + o] = part[0][o] + part[1][o] + b_k[o];
    } else if (tid < 256) {
      vrow[o] = part[2][o] + part[3][o] + b_v[o];
    }
    __syncthreads();
    // VW: 512 outputs = 1 per thread (h = chunk)
    {
      float a = 0.f;
      #pragma unroll 8
      for (int i = 0; i < 32; ++i)
        a += vrow[chunk * 32 + i] * W_go[(chunk * 32 + i) * 128 + o];
      vwl[chunk][o] = a;
    }
    __syncthreads();
    // VWM + TBL pack: 256 outputs (4h x 64o)
    if (tid < 256) {
      const int h = tid >> 6, oo = tid & 63;
      float m = 0.f;
      #pragma unroll 4
      for (int i = 0; i < 128; ++i)
        m += vwl[h][i] * ghl[i] * W_m1[(64 + i) * 64 + oo];
      TBL[(bt * 4 + h) * 64 + oo] =
          make_float4(vwl[h][2 * oo], vwl[h][2 * oo + 1], m, 0.f);
    }
  } else {
    // ---------------- consts ----------------
    const int o = tid;
    if (o < 64) {
      float wa = 0.f, wb = 0.f;
      #pragma unroll 4
      for (int h = 0; h < 64; ++h) {
        const float gw = ln_g[h] * W_m1[h * 64 + o];
        wa += W_nbr[h] * gw;
        wb += W_nbr[64 + h] * gw;
      }
      C[o] = wa; C[64 + o] = wb;
      float g = 0.f, p = 0.f;
      #pragma unroll 4
      for (int d = 0; d < 192; ++d) {
        const float w1 = W_m1[d * 64 + o];
        g += ln_g[d] * w1;
        p += ln_b[d] * w1;
      }
      C[128 + o] = g; C[192 + o] = p + b_m1[o];
      float c1 = 0.f;
      #pragma unroll 4
      for (int i = 0; i < 128; ++i)
        c1 += b_go[i] * ln_g[64 + i] * W_m1[(64 + i) * 64 + o];
      C[256 + o] = c1;
    }
  }
}

// ============ D[n,k] = S[knn[n,k]] . qlocal[n]  (batch-independent) ========
__global__ void precompute_D(const int* __restrict__ knn,
    const float* __restrict__ S, const float* __restrict__ qlocal,
    float* __restrict__ D)
{
  const int idx = blockIdx.x * 256 + threadIdx.x;
  const int n = idx >> 4;
  if (n >= NSN) return;
  const int j = knn[idx];
  const float4* Sr = (const float4*)(S + j * 64);
  const float4* Qr = (const float4*)(qlocal + n * 64);
  float acc = 0.f;
  #pragma unroll 4
  for (int i = 0; i < 16; ++i) {
    const float4 a = Sr[i]; const float4 q = Qr[i];
    acc += a.x * q.x + a.y * q.y + a.z * q.z + a.w * q.w;
  }
  D[idx] = acc;
}

// ============ Per-item precompute: KNN softmax + global-attn weights =======
__launch_bounds__(256, 2)
__global__ void precompute_item(const int* __restrict__ knn,
    const float* __restrict__ D, const float* __restrict__ c01,
    const float* __restrict__ x_flat, const int* __restrict__ mask,
    const float* __restrict__ qg, const float* __restrict__ kg,
    float* __restrict__ ATT, float2* __restrict__ AX, float* __restrict__ GAW)
{
  const int i = blockIdx.x * 256 + threadIdx.x;
  if (i >= NB * NSN) return;
  const int b = i / NSN;
  const int n = i - b * NSN;

  // ---- KNN attention ----
  int j[16];
  {
    const int4* kr = (const int4*)(knn + n * 16);
    const int4 a = kr[0], bb = kr[1], c = kr[2], d = kr[3];
    j[0]=a.x; j[1]=a.y; j[2]=a.z; j[3]=a.w;
    j[4]=bb.x; j[5]=bb.y; j[6]=bb.z; j[7]=bb.w;
    j[8]=c.x; j[9]=c.y; j[10]=c.z; j[11]=c.w;
    j[12]=d.x; j[13]=d.y; j[14]=d.z; j[15]=d.w;
  }
  float dg[16];
  {
    const float4* dr = (const float4*)(D + n * 16);
    const float4 a = dr[0], bb = dr[1], c = dr[2], d = dr[3];
    dg[0]=a.x; dg[1]=a.y; dg[2]=a.z; dg[3]=a.w;
    dg[4]=bb.x; dg[5]=bb.y; dg[6]=bb.z; dg[7]=bb.w;
    dg[8]=c.x; dg[9]=c.y; dg[10]=c.z; dg[11]=c.w;
    dg[12]=d.x; dg[13]=d.y; dg[14]=d.z; dg[15]=d.w;
  }
  const float2 cv = *(const float2*)(c01 + 2 * n);
  const float* xb = x_flat + (size_t)b * NSN * 2;
  const int* mb = mask + b * NSN;
  float x0[16], x1[16], lg[16];
  #pragma unroll 4
  for (int k = 0; k < 16; ++k) {
    const float2 xv = *(const float2*)(xb + 2 * j[k]);
    const int mk = mb[j[k]];
    x0[k] = xv.x; x1[k] = xv.y;
    const float l = (dg[k] + xv.x * cv.x + xv.y * cv.y) * 0.125f;
    lg[k] = (mk != 0) ? -10000.0f : l;
  }
  float mx = lg[0];
  #pragma unroll
  for (int k = 1; k < 16; ++k) mx = fmaxf(mx, lg[k]);
  float s = 0.f;
  #pragma unroll
  for (int k = 0; k < 16; ++k) { lg[k] = __expf(lg[k] - mx); s += lg[k]; }
  const float inv = 1.0f / s;
  float ax0 = 0.f, ax1 = 0.f;
  #pragma unroll
  for (int k = 0; k < 16; ++k) { lg[k] *= inv; ax0 += lg[k] * x0[k]; ax1 += lg[k] * x1[k]; }
  {
    float4* ao = (float4*)(ATT + (size_t)i * 16);
    ao[0] = make_float4(lg[0], lg[1], lg[2], lg[3]);
    ao[1] = make_float4(lg[4], lg[5], lg[6], lg[7]);
    ao[2] = make_float4(lg[8], lg[9], lg[10], lg[11]);
    ao[3] = make_float4(lg[12], lg[13], lg[14], lg[15]);
    AX[i] = make_float2(ax0, ax1);
  }

  // ---- global attention weights ----
  const float* qgr = qg + n * 128;
  const float* kgb = kg + b * NT * 128;
  #pragma unroll 1
  for (int h = 0; h < 4; ++h) {
    float4 q[8];
    const float4* q4 = (const float4*)(qgr + h * 32);
    #pragma unroll
    for (int u = 0; u < 8; ++u) q[u] = q4[u];
    float p[NT];
    #pragma unroll
    for (int t = 0; t < NT; ++t) {
      const float4* k4 = (const float4*)(kgb + t * 128 + h * 32);
      float a = 0.f;
      #pragma unroll
      for (int u = 0; u < 8; ++u) {
        const float4 kv = k4[u];
        a += q[u].x * kv.x + q[u].y * kv.y + q[u].z * kv.z + q[u].w * kv.w;
      }
      p[t] = a * 0.17677669529663687f;   // 1/sqrt(32)
    }
    float m2 = p[0];
    #pragma unroll
    for (int t = 1; t < NT; ++t) m2 = fmaxf(m2, p[t]);
    float s2 = 0.f;
    #pragma unroll
    for (int t = 0; t < NT; ++t) { p[t] = __expf(p[t] - m2); s2 += p[t]; }
    const float i2 = 1.0f / s2;
    float* go = GAW + (size_t)i * 24 + h * 6;
    #pragma unroll
    for (int t = 0; t < NT; ++t) go[t] = p[t] * i2;
  }
}

// ============ Main fused kernel: block = (b, 7 n-groups), wave = item ======
// (512,4): VGPR cap 64 (lean body, natural ~44-55); 1360 blocks, ~17us each
// so launch/drain ramp amortizes. #pragma unroll 1 guards VGPR.
__launch_bounds__(512, 4)
__global__ void fused_main(const int* __restrict__ mask,
    const int* __restrict__ knn, const float* __restrict__ Wnbr,
    const float2* __restrict__ SS, const float* __restrict__ ATT,
    const float2* __restrict__ AX, const float* __restrict__ GAW,
    const float4* __restrict__ TBL, const float* __restrict__ CONSTS,
    const float* __restrict__ bgo, const float* __restrict__ Wm2,
    const float* __restrict__ bm2, float* __restrict__ out)
{
  __shared__ __align__(16) float4 TBLl[NT * 4 * 64];  // 24 KB

  const int tid = threadIdx.x;
  const int b = blockIdx.x / NBLK;
  const int bg = blockIdx.x - b * NBLK;
  {
    const float4* tb = TBL + b * (NT * 4 * 64);
    for (int i = tid; i < NT * 4 * 64; i += 512) TBLl[i] = tb[i];
  }
  __syncthreads();

  const int w = tid >> 6, lane = tid & 63;

  // per-lane folded constants, reused across 7 items
  const float wa  = CONSTS[lane],       wbc = CONSTS[64 + lane];
  const float cg  = CONSTS[128 + lane], cp  = CONSTS[192 + lane];
  const float cc1 = CONSTS[256 + lane];
  const float w0 = Wnbr[lane], w1 = Wnbr[64 + lane];
  const float2 bgov = *(const float2*)(bgo + 2 * lane);
  const float wm2 = Wm2[lane], bm2s = bm2[0];

  #pragma unroll 1
  for (int ng = bg; ng < NGB; ng += NBLK) {
    const int n = ng * 8 + w;
    const int item = b * NSN + n;
    const int mself = mask[item];

    int jv = 0; float aw = 0.f;
    if (lane < 16) {
      jv = knn[n * 16 + lane];
      aw = ATT[(size_t)item * 16 + lane];
    }
    float gw = 0.f;
    if (lane < 24) gw = GAW[(size_t)item * 24 + lane];
    const float2 axv = AX[item];

    // ---- lf (lane=h) and L (lane=o): 16 packed float2 gathers, 4-batched ----
    float lf = axv.x * w0 + axv.y * w1;
    float L  = axv.x * wa + axv.y * wbc;
    #pragma unroll
    for (int kb = 0; kb < 4; ++kb) {
      const int j0 = __builtin_amdgcn_readlane(jv, 4 * kb + 0);
      const int j1 = __builtin_amdgcn_readlane(jv, 4 * kb + 1);
      const int j2 = __builtin_amdgcn_readlane(jv, 4 * kb + 2);
      const int j3 = __builtin_amdgcn_readlane(jv, 4 * kb + 3);
      const float a0 = rl_f(aw, 4 * kb + 0);
      const float a1 = rl_f(aw, 4 * kb + 1);
      const float a2 = rl_f(aw, 4 * kb + 2);
      const float a3 = rl_f(aw, 4 * kb + 3);
      const float2 s0 = SS[j0 * 64 + lane];
      const float2 s1 = SS[j1 * 64 + lane];
      const float2 s2 = SS[j2 * 64 + lane];
      const float2 s3 = SS[j3 * 64 + lane];
      lf += a0 * s0.x + a1 * s1.x + a2 * s2.x + a3 * s3.x;
      L  += a0 * s0.y + a1 * s1.y + a2 * s2.y + a3 * s3.y;
    }

    // ---- g_out + M from packed table with precomputed weights ----
    float g0 = bgov.x, g1 = bgov.y, M = 0.f;
    #pragma unroll 2
    for (int t = 0; t < NT; ++t) {
      const float4 r0 = TBLl[(t * 4 + 0) * 64 + lane];
      const float4 r1 = TBLl[(t * 4 + 1) * 64 + lane];
      const float4 r2 = TBLl[(t * 4 + 2) * 64 + lane];
      const float4 r3 = TBLl[(t * 4 + 3) * 64 + lane];
      const float a0 = rl_f(gw, t);
      const float a1 = rl_f(gw, 6 + t);
      const float a2 = rl_f(gw, 12 + t);
      const float a3 = rl_f(gw, 18 + t);
      g0 += a0 * r0.x + a1 * r1.x + a2 * r2.x + a3 * r3.x;
      g1 += a0 * r0.y + a1 * r1.y + a2 * r2.y + a3 * r3.y;
      M  += a0 * r0.z + a1 * r1.z + a2 * r2.z + a3 * r3.z;
    }

    // ---- LayerNorm stats over 192 ----
    float s1 = lf + g0 + g1;
    float s2 = lf * lf + g0 * g0 + g1 * g1;
    #pragma unroll
    for (int o = 32; o; o >>= 1) { s1 += __shfl_xor(s1, o); s2 += __shfl_xor(s2, o); }
    const float mu  = s1 * (1.0f / 192.0f);
    const float var = s2 * (1.0f / 192.0f) - mu * mu;
    const float rinv = rsqrtf(var + 1e-5f);

    // ---- folded MLP ----
    const float m1 = rinv * (L + M + cc1 - mu * cg) + cp;
    const float gelu = 0.5f * m1 * (1.0f + erff(m1 * 0.7071067811865476f));
    float pr = gelu * wm2;
    #pragma unroll
    for (int o = 32; o; o >>= 1) pr += __shfl_xor(pr, o);
    float res = pr + bm2s;
    if (mself == 0) res = 0.f;
    if (lane == 0) out[item] = res;
  }
}

extern "C" void kernel_launch(void* const* d_in, const int* in_sizes, int n_in,
                              void* d_out, int out_size, void* d_ws, size_t ws_size,
                              hipStream_t stream) {
  (void)in_sizes; (void)n_in; (void)out_size; (void)ws_size;
  const float* x_flat   = (const float*)d_in[0];
  const float* latent   = (const float*)d_in[1];
  const float* pos_emb  = (const float*)d_in[2];
  const float* face_emb = (const float*)d_in[3];
  const float* W_nbr = (const float*)d_in[4];
  const float* b_nbr = (const float*)d_in[5];
  const float* W_ql  = (const float*)d_in[6];
  const float* b_ql  = (const float*)d_in[7];
  const float* W_lat = (const float*)d_in[8];
  const float* b_lat = (const float*)d_in[9];
  const float* W_lf  = (const float*)d_in[10];
  const float* b_lf  = (const float*)d_in[11];
  const float* W_qg  = (const float*)d_in[12];
  const float* b_qg  = (const float*)d_in[13];
  const float* W_k   = (const float*)d_in[14];
  const float* b_k   = (const float*)d_in[15];
  const float* W_v   = (const float*)d_in[16];
  const float* b_v   = (const float*)d_in[17];
  const float* W_go  = (const float*)d_in[18];
  const float* b_go  = (const float*)d_in[19];
  const float* ln_g  = (const float*)d_in[20];
  const float* ln_b  = (const float*)d_in[21];
  const float* W_m1  = (const float*)d_in[22];
  const float* b_m1  = (const float*)d_in[23];
  const float* W_m2  = (const float*)d_in[24];
  const float* b_m2  = (const float*)d_in[25];
  const int* mask     = (const int*)d_in[26];
  const int* knn      = (const int*)d_in[27];
  const int* face_ids = (const int*)d_in[28];
  float* out = (float*)d_out;

  float* ws = (float*)d_ws;
  float* S      = ws;  ws += NSN * 64;
  float* qlocal = ws;  ws += NSN * 64;
  float* qgb    = ws;  ws += NSN * 128;
  float* c01    = ws;  ws += NSN * 2;
  float2* SSt   = (float2*)ws;  ws += NSN * 64 * 2;
  float* kgb    = ws;  ws += NB * NT * 128;
  float4* TBLt  = (float4*)ws;  ws += NB * NT * 4 * 64 * 4;
  float* CONSTS = ws;  ws += 5 * 64;
  float* Dt     = ws;  ws += NSN * KNN;
  float* ATTt   = ws;  ws += NB * NSN * KNN;
  float2* AXt   = (float2*)ws;  ws += NB * NSN * 2;
  float* GAWt   = ws;  ws += NB * NSN * 24;

  precompute_all<<<692, 512, 0, stream>>>(pos_emb, face_emb, face_ids,
      W_nbr, b_nbr, W_ql, b_ql, W_qg, b_qg,
      latent, W_lat, b_lat, W_lf, b_lf, W_k, b_k, W_v, b_v,
      W_go, b_go, W_m1, b_m1, ln_g, ln_b,
      S, qlocal, qgb, c01, SSt, kgb, TBLt, CONSTS);
  precompute_D<<<(NSN * KNN + 255) / 256, 256, 0, stream>>>(knn, S, qlocal, Dt);
  precompute_item<<<(NB * NSN + 255) / 256, 256, 0, stream>>>(knn, Dt, c01,
      x_flat, mask, qgb, kgb, ATTt, AXt, GAWt);
  fused_main<<<NB * NBLK, 512, 0, stream>>>(mask, knn, W_nbr,
      SSt, ATTt, AXt, GAWt, TBLt, CONSTS, b_go, W_m2, b_m2, out);
}